// Round 15
// baseline (78.541 us; speedup 1.0000x reference)
//
#include <hip/hip_runtime.h>

typedef float f4v __attribute__((ext_vector_type(4)));
typedef float f32x4 __attribute__((ext_vector_type(4)));
typedef __bf16 bf16x8 __attribute__((ext_vector_type(8)));
typedef unsigned short ushort8 __attribute__((ext_vector_type(8)));

static constexpr int KDIM = 2048;

// workspace layout (bytes)
static constexpr size_t OFF_XN      = 0;                                   // ushort [3][256][2048]   (3 MB)
static constexpr size_t OFF_D       = (size_t)3 * 256 * 2048 * 2;          // ushort [4][3][256][8192] (50.3 MB)
static constexpr size_t OFF_ROWLOSS = OFF_D + (size_t)4 * 3 * 256 * 8192 * 2; // float [768]

__device__ __forceinline__ unsigned short f2bf(float x) {
  union { float f; unsigned u; } c; c.f = x;
  unsigned r = c.u + 0x7fffu + ((c.u >> 16) & 1u);   // RNE
  return (unsigned short)(r >> 16);
}

__device__ __forceinline__ float bf2f(unsigned short u) {
  union { unsigned i; float f; } c; c.i = ((unsigned)u) << 16; return c.f;
}

__device__ __forceinline__ void gload_lds16(const void* g, void* l) {
  __builtin_amdgcn_global_load_lds((const __attribute__((address_space(1))) void*)g,
                                   (__attribute__((address_space(3))) void*)l,
                                   16, 0, 0);
}

// two f32x4 -> bf16x8 (compiler emits v_cvt_pk_bf16_f32)
__device__ __forceinline__ bf16x8 cvt8(f4v lo, f4v hi) {
  bf16x8 r;
  r[0] = (__bf16)lo[0]; r[1] = (__bf16)lo[1]; r[2] = (__bf16)lo[2]; r[3] = (__bf16)lo[3];
  r[4] = (__bf16)hi[0]; r[5] = (__bf16)hi[1]; r[6] = (__bf16)hi[2]; r[7] = (__bf16)hi[3];
  return r;
}

// ---------------- kernel 1: row-normalize inputs -> bf16 ----------------
__global__ __launch_bounds__(256) void k_normalize(
    const float* __restrict__ x0, const float* __restrict__ x1, const float* __restrict__ x2,
    unsigned short* __restrict__ xn)
{
  int bid = blockIdx.x;            // 0..767 : branch*256 + row
  int branch = bid >> 8;
  int row = bid & 255;
  const float* src = (branch == 0 ? x0 : (branch == 1 ? x1 : x2)) + (size_t)row * KDIM;
  int tid = threadIdx.x;
  f4v a = *(const f4v*)(src + tid * 8);
  f4v b = *(const f4v*)(src + tid * 8 + 4);
  float s = a[0]*a[0] + a[1]*a[1] + a[2]*a[2] + a[3]*a[3]
          + b[0]*b[0] + b[1]*b[1] + b[2]*b[2] + b[3]*b[3];
  #pragma unroll
  for (int m = 1; m < 64; m <<= 1) s += __shfl_xor(s, m);
  __shared__ float ls[4];
  if ((tid & 63) == 0) ls[tid >> 6] = s;
  __syncthreads();
  float total = ls[0] + ls[1] + ls[2] + ls[3];
  float inv = 1.0f / fmaxf(sqrtf(total), 1e-12f);
  ushort8 u;
  #pragma unroll
  for (int e = 0; e < 4; ++e) u[e]     = f2bf(a[e] * inv);
  #pragma unroll
  for (int e = 0; e < 4; ++e) u[4 + e] = f2bf(b[e] * inv);
  *(ushort8*)(xn + (size_t)bid * KDIM + tid * 8) = u;
}

// ---------------- kernel 2: K-split-4 GEMM, BK=64, single-buffered ----------------
// BM=256, BN=128, BK=64, K-split 4 (each block K=512, 8 tiles). Grid = 768
// balanced blocks x 512 thr (8 waves, 4M x 2N, wave-tile 64x64); LDS 48 KB
// single-buffered (3 blocks/CU) with r8's 2-barrier loop.
// Staged volume minimal: A 192 MB + B 192 MB.
// A (bf16): global_load_lds, pre-swizzled source (r5/r11-proven, 0 conflicts).
// B (f32): global->reg (4 f4v) -> cvt_pk bf16 -> swizzled 16B ds_write.
// Output: partial dot tile as bf16 to dW (epilogue in k_row).
__global__ __launch_bounds__(512, 4) void k_gemm(
    const unsigned short* __restrict__ xn,
    const float* __restrict__ f0, const float* __restrict__ f1, const float* __restrict__ f2,
    unsigned short* __restrict__ dW)
{
  // A [0,32768): 256 rows x 128B (8 chunks16, chunk ^ row&7), bf16
  // B [32768,49152): 128 cols x 128B (8 chunks16, chunk ^ col&7), bf16
  __shared__ char lds[49152];

  int bid = blockIdx.x;
  int swz = (bid & 7) * 96 + (bid >> 3);   // XCD-aware, 768 % 8 == 0 -> bijective
  int branch = swz >> 8;                   // 256 blocks per branch
  int rem = swz & 255;
  int ntile = rem >> 2;                    // 64 n-tiles of 128 cols
  int ks = rem & 3;                        // K quarter (512 each)

  const unsigned short* A = xn + (size_t)branch * 256 * KDIM + ks * 512;
  const float* F = (branch == 0 ? f0 : (branch == 1 ? f1 : f2))
                 + (size_t)ntile * 128 * KDIM + ks * 512;

  int tid = threadIdx.x;                   // 0..511
  int wave = tid >> 6;
  int lane = tid & 63;
  int rcol0 = lane & 15;
  int klane = lane >> 4;
  int wr = wave >> 1;    // M quadrant (0..3), 64 rows
  int wc = wave & 1;     // N half (0..1), 64 cols

  // ---- A staging: 4 x gload_lds(16B)/thread. c = g*512+tid: row = g*64+(tid>>3),
  // phys chunk = tid&7, logical = (tid&7) ^ (row&7); row&7 = (tid>>3)&7 indep of g.
  const unsigned short* aSrc = A + (size_t)(tid >> 3) * KDIM
                             + (((tid & 7) ^ ((tid >> 3) & 7)) << 3);
  char* aDst = lds + wave * 1024;          // + g*8192

#define STAGE_A(kt) do { \
    _Pragma("unroll") for (int g = 0; g < 4; ++g) \
      gload_lds16(aSrc + (size_t)g * 64 * KDIM + (kt) * 64, \
                  aDst + g * 8192); \
  } while (0)

  // ---- B global loads: 2 chunks of 8 floats/thread. c = g*512+tid:
  // col = g*64+(tid>>3), kchunk8 = tid&7 (one 8-float group = one 16B bf16 chunk).
  const float* bSrc = F + (size_t)(tid >> 3) * KDIM + (tid & 7) * 8;
  f4v b0lo, b0hi, b1lo, b1hi;

#define LOADB_G(kt) do { \
    b0lo = *(const f4v*)(bSrc + (kt) * 64); \
    b0hi = *(const f4v*)(bSrc + (kt) * 64 + 4); \
    b1lo = *(const f4v*)(bSrc + (size_t)64 * KDIM + (kt) * 64); \
    b1hi = *(const f4v*)(bSrc + (size_t)64 * KDIM + (kt) * 64 + 4); \
  } while (0)

  // ---- B LDS write: byte = 32768 + col*128 + (((tid&7) ^ (col&7))<<4); col&7=(tid>>3)&7
  int bOff = 32768 + (tid >> 3) * 128
           + (((tid & 7) ^ ((tid >> 3) & 7)) << 4);

#define WRITE_B() do { \
    *(bf16x8*)(lds + bOff)        = cvt8(b0lo, b0hi); \
    *(bf16x8*)(lds + bOff + 8192) = cvt8(b1lo, b1hi); \
  } while (0)

  f32x4 acc[4][4];
  #pragma unroll
  for (int i = 0; i < 4; ++i)
    #pragma unroll
    for (int j = 0; j < 4; ++j)
      #pragma unroll
      for (int q = 0; q < 4; ++q) acc[i][j][q] = 0.0f;

  int sa = rcol0 & 7;
  const char* aRd = lds + (wr * 64 + rcol0) * 128;           // + i*2048 + ch
  const char* bRd = lds + 32768 + (wc * 64 + rcol0) * 128;   // + j*2048 + ch

#define COMPUTE() do { \
    _Pragma("unroll") for (int ksl = 0; ksl < 2; ++ksl) { \
      int ch = (((ksl * 4 + klane) ^ sa) << 4); \
      bf16x8 a0 = *(const bf16x8*)(aRd + ch); \
      bf16x8 a1 = *(const bf16x8*)(aRd + 2048 + ch); \
      bf16x8 a2 = *(const bf16x8*)(aRd + 4096 + ch); \
      bf16x8 a3 = *(const bf16x8*)(aRd + 6144 + ch); \
      _Pragma("unroll") for (int j = 0; j < 4; ++j) { \
        bf16x8 bj = *(const bf16x8*)(bRd + j * 2048 + ch); \
        acc[0][j] = __builtin_amdgcn_mfma_f32_16x16x32_bf16(a0, bj, acc[0][j], 0, 0, 0); \
        acc[1][j] = __builtin_amdgcn_mfma_f32_16x16x32_bf16(a1, bj, acc[1][j], 0, 0, 0); \
        acc[2][j] = __builtin_amdgcn_mfma_f32_16x16x32_bf16(a2, bj, acc[2][j], 0, 0, 0); \
        acc[3][j] = __builtin_amdgcn_mfma_f32_16x16x32_bf16(a3, bj, acc[3][j], 0, 0, 0); \
      } \
    } \
  } while (0)

  // r8's single-buffered 2-barrier loop, 8 tiles of BK=64
  LOADB_G(0);
  STAGE_A(0);
  WRITE_B();
  __syncthreads();
  for (int kt = 0; kt < 8; ++kt) {
    if (kt < 7) LOADB_G(kt + 1);   // issue next B loads early (covered by compute)
    COMPUTE();
    __syncthreads();
    if (kt < 7) {
      STAGE_A(kt + 1);
      WRITE_B();
      __syncthreads();
    }
  }

#undef STAGE_A
#undef LOADB_G
#undef WRITE_B
#undef COMPUTE

  // write partial dot tile as bf16: D[ks][branch][row][col]
  unsigned short* Dp = dW + ((size_t)(ks * 3 + branch)) * 256 * 8192
                     + (size_t)ntile * 128 + (size_t)wc * 64 + rcol0;
  #pragma unroll
  for (int i = 0; i < 4; ++i) {
    #pragma unroll
    for (int q = 0; q < 4; ++q) {
      int row = wr * 64 + i * 16 + (klane << 2) + q;
      unsigned short* rp = Dp + (size_t)row * 8192;
      #pragma unroll
      for (int j = 0; j < 4; ++j) rp[j * 16] = f2bf(acc[i][j][q]);
    }
  }
}

// ---------------- kernel 3: per-row epilogue ----------------
// Adds the four K-split partials, computes s1..s4 sums + target dot, emits rowloss.
__global__ __launch_bounds__(256) void k_row(
    const unsigned short* __restrict__ dW,
    const int* __restrict__ targets,
    float* __restrict__ rowloss)
{
  int row = blockIdx.x;    // 0..767 = branch*256 + r
  int tid = threadIdx.x;   // 256, each covers 32 cols
  const size_t SPLIT = (size_t)3 * 256 * 8192;
  const unsigned short* p0 = dW + (size_t)row * 8192 + tid * 32;
  int tgt = targets[row & 255];
  int cbase = tid * 32;

  float s1 = 0.f, s2 = 0.f, s3 = 0.f, s4 = 0.f, dt = 0.f;
  #pragma unroll
  for (int g = 0; g < 4; ++g) {
    ushort8 u0 = *(const ushort8*)(p0 + g * 8);
    ushort8 u1 = *(const ushort8*)(p0 + SPLIT + g * 8);
    ushort8 u2 = *(const ushort8*)(p0 + 2 * SPLIT + g * 8);
    ushort8 u3 = *(const ushort8*)(p0 + 3 * SPLIT + g * 8);
    #pragma unroll
    for (int e = 0; e < 8; ++e) {
      float d = (bf2f(u0[e]) + bf2f(u1[e])) + (bf2f(u2[e]) + bf2f(u3[e]));
      float e1 = __expf(fmaf(20.0f, d, -20.0f));
      float Dv = sqrtf(fmaxf(2.0f - 2.0f * d, 0.0f));
      float e2 = __expf(Dv - 2.0f);
      s1 += e1; s2 += e2;
      float t2 = e2 * e2;
      s3 += t2; s4 += t2 * e2;
      if (cbase + g * 8 + e == tgt) dt = d;   // exactly one col matches globally
    }
  }
  #pragma unroll
  for (int m = 1; m < 64; m <<= 1) {
    s1 += __shfl_xor(s1, m); s2 += __shfl_xor(s2, m);
    s3 += __shfl_xor(s3, m); s4 += __shfl_xor(s4, m);
    dt += __shfl_xor(dt, m);
  }
  __shared__ float ls[5][4];
  if ((tid & 63) == 0) {
    int w = tid >> 6;
    ls[0][w] = s1; ls[1][w] = s2; ls[2][w] = s3; ls[3][w] = s4; ls[4][w] = dt;
  }
  __syncthreads();
  if (tid == 0) {
    float p1s = ls[0][0] + ls[0][1] + ls[0][2] + ls[0][3];
    float Z1  = ls[1][0] + ls[1][1] + ls[1][2] + ls[1][3];
    float Z2  = ls[2][0] + ls[2][1] + ls[2][2] + ls[2][3];
    float Z3  = ls[3][0] + ls[3][1] + ls[3][2] + ls[3][3];
    float dtv = ls[4][0] + ls[4][1] + ls[4][2] + ls[4][3];
    // CE1 = logsumexp(20*dot) - 20*dot_t   (fixed shift 20: 20d-20 <= ~0)
    float CE1 = 20.0f + logf(p1s) - 20.0f * dtv;
    // CE2 = log(sum_n exp(S_n)) - S_t ; sum_n exp(S_n) = N + 1 + Z2/(2 Z1^2) + Z3/(6 Z1^3)
    float Dt = sqrtf(fmaxf(2.0f - 2.0f * dtv, 0.0f));
    float St = __expf(Dt - 2.0f) / Z1;
    float sES = 8193.0f + Z2 / (2.0f * Z1 * Z1) + Z3 / (6.0f * Z1 * Z1 * Z1);
    float CE2 = logf(sES) - St;
    rowloss[row] = (CE1 + CE2) * (0.5f / 256.0f);
  }
}

// ---------------- kernel 4: final sum ----------------
__global__ __launch_bounds__(256) void k_final(const float* __restrict__ rowloss, float* __restrict__ out)
{
  int tid = threadIdx.x;
  float v = rowloss[tid] + rowloss[tid + 256] + rowloss[tid + 512];
  #pragma unroll
  for (int m = 1; m < 64; m <<= 1) v += __shfl_xor(v, m);
  __shared__ float ls[4];
  if ((tid & 63) == 0) ls[tid >> 6] = v;
  __syncthreads();
  if (tid == 0) out[0] = ls[0] + ls[1] + ls[2] + ls[3];
}

extern "C" void kernel_launch(void* const* d_in, const int* in_sizes, int n_in,
                              void* d_out, int out_size, void* d_ws, size_t ws_size,
                              hipStream_t stream) {
  const float* in0 = (const float*)d_in[0];
  const float* in1 = (const float*)d_in[1];
  const float* in2 = (const float*)d_in[2];
  const int* targets = (const int*)d_in[3];
  // d_in[4] = epoch (unused by the loss)
  const float* f0 = (const float*)d_in[5];
  const float* f1 = (const float*)d_in[6];
  const float* f2 = (const float*)d_in[7];

  char* ws = (char*)d_ws;
  unsigned short* xn = (unsigned short*)(ws + OFF_XN);
  unsigned short* dW = (unsigned short*)(ws + OFF_D);
  float* rowloss = (float*)(ws + OFF_ROWLOSS);
  float* out = (float*)d_out;

  k_normalize<<<768, 256, 0, stream>>>(in0, in1, in2, xn);
  k_gemm<<<768, 512, 0, stream>>>(xn, f0, f1, f2, dW);
  k_row<<<768, 256, 0, stream>>>(dW, targets, rowloss);
  k_final<<<1, 256, 0, stream>>>(rowloss, out);
}

// Round 16
// 62.355 us; speedup vs baseline: 1.2596x; 1.2596x over previous
//
#include <hip/hip_runtime.h>

typedef float f4v __attribute__((ext_vector_type(4)));
typedef float f32x4 __attribute__((ext_vector_type(4)));
typedef __bf16 bf16x8 __attribute__((ext_vector_type(8)));
typedef __bf16 bf16x4 __attribute__((ext_vector_type(4)));
typedef unsigned short ushort8 __attribute__((ext_vector_type(8)));

static constexpr int KDIM = 2048;

// workspace layout (bytes)
static constexpr size_t OFF_XN      = 0;                                   // ushort [3][256][2048]  (3 MB)
static constexpr size_t OFF_D       = (size_t)3 * 256 * 2048 * 2;          // ushort [2][3][256][8192] (25.2 MB)
static constexpr size_t OFF_ROWLOSS = OFF_D + (size_t)2 * 3 * 256 * 8192 * 2; // float [768]

__device__ __forceinline__ unsigned short f2bf(float x) {
  union { float f; unsigned u; } c; c.f = x;
  unsigned r = c.u + 0x7fffu + ((c.u >> 16) & 1u);   // RNE
  return (unsigned short)(r >> 16);
}

__device__ __forceinline__ float bf2f(unsigned short u) {
  union { unsigned i; float f; } c; c.i = ((unsigned)u) << 16; return c.f;
}

__device__ __forceinline__ void gload_lds16(const void* g, void* l) {
  __builtin_amdgcn_global_load_lds((const __attribute__((address_space(1))) void*)g,
                                   (__attribute__((address_space(3))) void*)l,
                                   16, 0, 0);
}

// f32x4 -> bf16x4 (v_cvt_pk_bf16_f32 pair) -> 8B LDS store
__device__ __forceinline__ void cvt_store8(char* p, f4v v) {
  bf16x4 o;
  o[0] = (__bf16)v[0]; o[1] = (__bf16)v[1]; o[2] = (__bf16)v[2]; o[3] = (__bf16)v[3];
  *(bf16x4*)p = o;
}

// ---------------- kernel 1: row-normalize inputs -> bf16 ----------------
__global__ __launch_bounds__(256) void k_normalize(
    const float* __restrict__ x0, const float* __restrict__ x1, const float* __restrict__ x2,
    unsigned short* __restrict__ xn)
{
  int bid = blockIdx.x;            // 0..767 : branch*256 + row
  int branch = bid >> 8;
  int row = bid & 255;
  const float* src = (branch == 0 ? x0 : (branch == 1 ? x1 : x2)) + (size_t)row * KDIM;
  int tid = threadIdx.x;
  f4v a = *(const f4v*)(src + tid * 8);
  f4v b = *(const f4v*)(src + tid * 8 + 4);
  float s = a[0]*a[0] + a[1]*a[1] + a[2]*a[2] + a[3]*a[3]
          + b[0]*b[0] + b[1]*b[1] + b[2]*b[2] + b[3]*b[3];
  #pragma unroll
  for (int m = 1; m < 64; m <<= 1) s += __shfl_xor(s, m);
  __shared__ float ls[4];
  if ((tid & 63) == 0) ls[tid >> 6] = s;
  __syncthreads();
  float total = ls[0] + ls[1] + ls[2] + ls[3];
  float inv = 1.0f / fmaxf(sqrtf(total), 1e-12f);
  ushort8 u;
  #pragma unroll
  for (int e = 0; e < 4; ++e) u[e]     = f2bf(a[e] * inv);
  #pragma unroll
  for (int e = 0; e < 4; ++e) u[4 + e] = f2bf(b[e] * inv);
  *(ushort8*)(xn + (size_t)bid * KDIM + tid * 8) = u;
}

// ---------------- kernel 2: K-split GEMM (round-11 best configuration) ----------------
// BM=256 (whole batch), BN=128, BK=32, K-split 2 (each block does K/2=1024).
// Grid = 3 x 64 ntiles x 2 ksplit = 384 blocks x 512 thr (8 waves).
// Staged volume minimal: A 192 MB + B 192 MB (each B element read once).
// 8 waves as 4M x 2N, wave-tile 64x64.
// A (bf16): global_load_lds, source pre-swizzled (chunk ^ (row>>1)&3), linear dest.
// B (f32): global->reg (2 f4v) -> cvt_pk bf16 -> swizzled 8B ds_write.
// Output: partial dot tile as bf16 to workspace (epilogue math in k_row).
__global__ __launch_bounds__(512, 4) void k_gemm(
    const unsigned short* __restrict__ xn,
    const float* __restrict__ f0, const float* __restrict__ f1, const float* __restrict__ f2,
    unsigned short* __restrict__ dW)
{
  // per buffer (24 KB): A [0,16384) = 256 rows x 64B (4 chunks16, chunk ^ (row>>1)&3)
  //                     B [16384,24576) = 128 cols x 64B (4 chunks16, chunk ^ (col>>1)&3)
  __shared__ char lds[2 * 24576];

  int bid = blockIdx.x;
  int swz = (bid & 7) * 48 + (bid >> 3);   // XCD-aware, 384 % 8 == 0 -> bijective
  int branch = swz >> 7;                   // 128 blocks per branch
  int rem = swz & 127;
  int ntile = rem >> 1;                    // 64 n-tiles of 128 cols
  int ks = rem & 1;                        // K half

  const unsigned short* A = xn + (size_t)branch * 256 * KDIM + ks * 1024;
  const float* F = (branch == 0 ? f0 : (branch == 1 ? f1 : f2))
                 + (size_t)ntile * 128 * KDIM + ks * 1024;

  int tid = threadIdx.x;                   // 0..511
  int wave = tid >> 6;
  int lane = tid & 63;
  int rcol0 = lane & 15;
  int klane = lane >> 4;
  int wr = wave >> 1;    // M quadrant (0..3), 64 rows
  int wc = wave & 1;     // N half (0..1), 64 cols

  // ---- A staging: 2 x gload_lds(16B)/thread. c = g*512+tid: row = g*128+(tid>>2),
  // phys chunk = tid&3, logical = (tid&3) ^ ((row>>1)&3); (row>>1)&3 indep of g.
  const unsigned short* aSrc = A + (size_t)(tid >> 2) * KDIM
                             + (((tid & 3) ^ ((tid >> 3) & 3)) << 3);
  char* aDst = lds + wave * 1024;          // + buf*24576 + g*8192

#define STAGE_A(kt, buf) do { \
    gload_lds16(aSrc + (kt) * 32, aDst + (buf) * 24576); \
    gload_lds16(aSrc + (size_t)128 * KDIM + (kt) * 32, aDst + (buf) * 24576 + 8192); \
  } while (0)

  // ---- B global loads: 2 f4v/thread. col = g*64+(tid>>3), f4v idx v = tid&7.
  const float* bSrc = F + (size_t)(tid >> 3) * KDIM + (tid & 7) * 4;
  f4v bq0, bq1;

#define LOADB_G(kt) do { \
    bq0 = *(const f4v*)(bSrc + (kt) * 32); \
    bq1 = *(const f4v*)(bSrc + (size_t)64 * KDIM + (kt) * 32); \
  } while (0)

  // ---- B LDS write: chunk16 = v>>1, half = v&1, swizzle s = (col>>1)&3 = (tid>>4)&3
  int bOff = 16384 + (tid >> 3) * 64
           + (((((tid & 7) >> 1)) ^ ((tid >> 4) & 3)) << 4) + (tid & 1) * 8;

#define WRITE_B(buf) do { \
    char* wb = lds + (buf) * 24576 + bOff; \
    cvt_store8(wb, bq0); \
    cvt_store8(wb + 4096, bq1); \
  } while (0)

  f32x4 acc[4][4];
  #pragma unroll
  for (int i = 0; i < 4; ++i)
    #pragma unroll
    for (int j = 0; j < 4; ++j)
      #pragma unroll
      for (int q = 0; q < 4; ++q) acc[i][j][q] = 0.0f;

  int sx = (rcol0 >> 1) & 3;               // read swizzle, same for A and B
  int ch = ((klane ^ sx) << 4);
  const char* aRd = lds + (wr * 64 + rcol0) * 64;            // + i*1024 + ch + buf*24576
  const char* bRd = lds + 16384 + (wc * 64 + rcol0) * 64;    // + j*1024 + ch + buf*24576

#define COMPUTE(buf) do { \
    const char* ra = aRd + (buf) * 24576 + ch; \
    const char* rb = bRd + (buf) * 24576 + ch; \
    bf16x8 a0 = *(const bf16x8*)(ra); \
    bf16x8 a1 = *(const bf16x8*)(ra + 1024); \
    bf16x8 a2 = *(const bf16x8*)(ra + 2048); \
    bf16x8 a3 = *(const bf16x8*)(ra + 3072); \
    _Pragma("unroll") for (int j = 0; j < 4; ++j) { \
      bf16x8 bj = *(const bf16x8*)(rb + j * 1024); \
      acc[0][j] = __builtin_amdgcn_mfma_f32_16x16x32_bf16(a0, bj, acc[0][j], 0, 0, 0); \
      acc[1][j] = __builtin_amdgcn_mfma_f32_16x16x32_bf16(a1, bj, acc[1][j], 0, 0, 0); \
      acc[2][j] = __builtin_amdgcn_mfma_f32_16x16x32_bf16(a2, bj, acc[2][j], 0, 0, 0); \
      acc[3][j] = __builtin_amdgcn_mfma_f32_16x16x32_bf16(a3, bj, acc[3][j], 0, 0, 0); \
    } \
  } while (0)

  // 2-phase double-buffered loop, 32 tiles of BK=32 (K-range 1024)
  LOADB_G(0);
  STAGE_A(0, 0);
  WRITE_B(0);
  __syncthreads();

  for (int kt = 0; kt < 32; ++kt) {
    int cur = kt & 1;
    if (kt < 31) {
      LOADB_G(kt + 1);          // issue HBM loads early
      STAGE_A(kt + 1, cur ^ 1);
    }
    COMPUTE(cur);
    if (kt < 31) WRITE_B(cur ^ 1);
    __syncthreads();
  }

#undef STAGE_A
#undef LOADB_G
#undef WRITE_B
#undef COMPUTE

  // write partial dot tile as bf16: D[ks][branch][row][col]
  unsigned short* Dp = dW + ((size_t)(ks * 3 + branch)) * 256 * 8192
                     + (size_t)ntile * 128 + (size_t)wc * 64 + rcol0;
  #pragma unroll
  for (int i = 0; i < 4; ++i) {
    #pragma unroll
    for (int q = 0; q < 4; ++q) {
      int row = wr * 64 + i * 16 + (klane << 2) + q;
      unsigned short* rp = Dp + (size_t)row * 8192;
      #pragma unroll
      for (int j = 0; j < 4; ++j) rp[j * 16] = f2bf(acc[i][j][q]);
    }
  }
}

// ---------------- kernel 3: per-row epilogue ----------------
// Adds the two K-split partials, computes s1..s4 sums + target dot, emits rowloss.
__global__ __launch_bounds__(256) void k_row(
    const unsigned short* __restrict__ dW,
    const int* __restrict__ targets,
    float* __restrict__ rowloss)
{
  int row = blockIdx.x;    // 0..767 = branch*256 + r
  int tid = threadIdx.x;   // 256, each covers 32 cols
  const size_t SPLIT = (size_t)3 * 256 * 8192;
  const unsigned short* p0 = dW + (size_t)row * 8192 + tid * 32;
  const unsigned short* p1 = p0 + SPLIT;
  int tgt = targets[row & 255];
  int cbase = tid * 32;

  float s1 = 0.f, s2 = 0.f, s3 = 0.f, s4 = 0.f, dt = 0.f;
  #pragma unroll
  for (int g = 0; g < 4; ++g) {
    ushort8 u0 = *(const ushort8*)(p0 + g * 8);
    ushort8 u1 = *(const ushort8*)(p1 + g * 8);
    #pragma unroll
    for (int e = 0; e < 8; ++e) {
      float d = bf2f(u0[e]) + bf2f(u1[e]);
      float e1 = __expf(fmaf(20.0f, d, -20.0f));
      float Dv = sqrtf(fmaxf(2.0f - 2.0f * d, 0.0f));
      float e2 = __expf(Dv - 2.0f);
      s1 += e1; s2 += e2;
      float t2 = e2 * e2;
      s3 += t2; s4 += t2 * e2;
      if (cbase + g * 8 + e == tgt) dt = d;   // exactly one col matches globally
    }
  }
  #pragma unroll
  for (int m = 1; m < 64; m <<= 1) {
    s1 += __shfl_xor(s1, m); s2 += __shfl_xor(s2, m);
    s3 += __shfl_xor(s3, m); s4 += __shfl_xor(s4, m);
    dt += __shfl_xor(dt, m);
  }
  __shared__ float ls[5][4];
  if ((tid & 63) == 0) {
    int w = tid >> 6;
    ls[0][w] = s1; ls[1][w] = s2; ls[2][w] = s3; ls[3][w] = s4; ls[4][w] = dt;
  }
  __syncthreads();
  if (tid == 0) {
    float p1s = ls[0][0] + ls[0][1] + ls[0][2] + ls[0][3];
    float Z1  = ls[1][0] + ls[1][1] + ls[1][2] + ls[1][3];
    float Z2  = ls[2][0] + ls[2][1] + ls[2][2] + ls[2][3];
    float Z3  = ls[3][0] + ls[3][1] + ls[3][2] + ls[3][3];
    float dtv = ls[4][0] + ls[4][1] + ls[4][2] + ls[4][3];
    // CE1 = logsumexp(20*dot) - 20*dot_t   (fixed shift 20: 20d-20 <= ~0)
    float CE1 = 20.0f + logf(p1s) - 20.0f * dtv;
    // CE2 = log(sum_n exp(S_n)) - S_t ; sum_n exp(S_n) = N + 1 + Z2/(2 Z1^2) + Z3/(6 Z1^3)
    float Dt = sqrtf(fmaxf(2.0f - 2.0f * dtv, 0.0f));
    float St = __expf(Dt - 2.0f) / Z1;
    float sES = 8193.0f + Z2 / (2.0f * Z1 * Z1) + Z3 / (6.0f * Z1 * Z1 * Z1);
    float CE2 = logf(sES) - St;
    rowloss[row] = (CE1 + CE2) * (0.5f / 256.0f);
  }
}

// ---------------- kernel 4: final sum ----------------
__global__ __launch_bounds__(256) void k_final(const float* __restrict__ rowloss, float* __restrict__ out)
{
  int tid = threadIdx.x;
  float v = rowloss[tid] + rowloss[tid + 256] + rowloss[tid + 512];
  #pragma unroll
  for (int m = 1; m < 64; m <<= 1) v += __shfl_xor(v, m);
  __shared__ float ls[4];
  if ((tid & 63) == 0) ls[tid >> 6] = v;
  __syncthreads();
  if (tid == 0) out[0] = ls[0] + ls[1] + ls[2] + ls[3];
}

extern "C" void kernel_launch(void* const* d_in, const int* in_sizes, int n_in,
                              void* d_out, int out_size, void* d_ws, size_t ws_size,
                              hipStream_t stream) {
  const float* in0 = (const float*)d_in[0];
  const float* in1 = (const float*)d_in[1];
  const float* in2 = (const float*)d_in[2];
  const int* targets = (const int*)d_in[3];
  // d_in[4] = epoch (unused by the loss)
  const float* f0 = (const float*)d_in[5];
  const float* f1 = (const float*)d_in[6];
  const float* f2 = (const float*)d_in[7];

  char* ws = (char*)d_ws;
  unsigned short* xn = (unsigned short*)(ws + OFF_XN);
  unsigned short* dW = (unsigned short*)(ws + OFF_D);
  float* rowloss = (float*)(ws + OFF_ROWLOSS);
  float* out = (float*)d_out;

  k_normalize<<<768, 256, 0, stream>>>(in0, in1, in2, xn);
  k_gemm<<<384, 512, 0, stream>>>(xn, f0, f1, f2, dW);
  k_row<<<768, 256, 0, stream>>>(dW, targets, rowloss);
  k_final<<<1, 256, 0, stream>>>(rowloss, out);
}